// Round 3
// baseline (2003.494 us; speedup 1.0000x reference)
//
#include <hip/hip_runtime.h>
#include <hip/hip_bf16.h>
#include <cstdint>

typedef unsigned int u32;
typedef unsigned short u16;

#define TT 128
#define BB 512
#define DD 128
#define HH 256
#define CC 512

__device__ __forceinline__ u16 f2bf(float f){
  u32 u = __builtin_bit_cast(u32, f);
  u += 0x7FFFu + ((u >> 16) & 1u);
  return (u16)(u >> 16);
}
__device__ __forceinline__ float bflo(u32 w){ return __builtin_bit_cast(float, w << 16); }
__device__ __forceinline__ float bfhi(u32 w){ return __builtin_bit_cast(float, w & 0xFFFF0000u); }
__device__ __forceinline__ float bf1(u16 w){ return __builtin_bit_cast(float, ((u32)w) << 16); }
__device__ __forceinline__ float sigm(float x){ return 1.f / (1.f + __expf(-x)); }
__device__ __forceinline__ float tanh_fast(float x){
  float t = __expf(-2.f * fabsf(x));
  float r = (1.f - t) / (1.f + t);
  return copysignf(r, x);
}

// Kernel 0: pack weights to bf16, transposed [k][n] for coalesced per-k access.
// pre part: A = [x_eff(128) | m(128)]; k<128 -> col k (x-part), k>=128 -> col k+256 (m-part, D+H+(k-128))
// rec part: col = 128+k (h slice of combined)
__global__ void prep_weights(const float* __restrict__ zl_w, const float* __restrict__ rl_w,
                             const float* __restrict__ hl_w, const float* __restrict__ gh_w,
                             u32* __restrict__ zr_preT, u16* __restrict__ h_preT,
                             u32* __restrict__ zr_recT, u16* __restrict__ h_recT,
                             u16* __restrict__ ghT){
  int k = blockIdx.x;   // 0..255
  int n = threadIdx.x;  // 0..255
  int colp = (k < 128) ? k : (k + 256);
  zr_preT[k*HH + n] = (u32)f2bf(zl_w[n*CC + colp]) | ((u32)f2bf(rl_w[n*CC + colp]) << 16);
  h_preT[k*HH + n]  = f2bf(hl_w[n*CC + colp]);
  int colr = 128 + k;
  zr_recT[k*HH + n] = (u32)f2bf(zl_w[n*CC + colr]) | ((u32)f2bf(rl_w[n*CC + colr]) << 16);
  h_recT[k*HH + n]  = f2bf(hl_w[n*CC + colr]);
  if (k < 128) ghT[k*HH + n] = f2bf(gh_w[n*DD + k]);
}

// Kernel 1: precompute z_pre/r_pre/h_pre (K=256 GEMM) and delta_h (K=128 GEMM) for all (t,b).
// Block = 16 rows (one t, 16 consecutive b), 256 threads; thread owns output column n.
__global__ __launch_bounds__(256) void precompute(
    const float* __restrict__ input, const float* __restrict__ xmean,
    const float* __restrict__ gx_w, const float* __restrict__ gx_b,
    const float* __restrict__ zl_b, const float* __restrict__ rl_b,
    const float* __restrict__ hl_b, const float* __restrict__ gh_b,
    const u32* __restrict__ zr_preT, const u16* __restrict__ h_preT, const u16* __restrict__ ghT,
    float* __restrict__ zpre, float* __restrict__ rpre, float* __restrict__ hpre,
    float* __restrict__ dh){
  __shared__ float A[16][260];    // [row][ x_eff(128) | m(128) ], padded
  __shared__ float Dl[16][132];   // Delta, padded
  int r0 = blockIdx.x * 16;       // global row = t*BB + b
  int t  = r0 >> 9;
  int b0 = r0 & 511;
  int tid = threadIdx.x;
  {
    int i = tid >> 4, j = tid & 15;
    int b = b0 + i, d0 = j * 8;
    const float* px  = input + (((size_t)(b*4 + 0)*TT + t)*DD + d0);
    const float* pxl = input + (((size_t)(b*4 + 1)*TT + t)*DD + d0);
    const float* pm  = input + (((size_t)(b*4 + 2)*TT + t)*DD + d0);
    const float* pd  = input + (((size_t)(b*4 + 3)*TT + t)*DD + d0);
    const float* pxm = xmean + t*DD + d0;
    #pragma unroll
    for (int jj = 0; jj < 8; ++jj){
      int d = d0 + jj;
      float x = px[jj], xl = pxl[jj], m = pm[jj], dl = pd[jj];
      float dxv = __expf(-fmaxf(dl * gx_w[d*DD + d] + gx_b[d], 0.f));
      float xe  = m*x + (1.f - m)*(dxv*xl + (1.f - dxv)*pxm[jj]);
      A[i][d] = xe;
      A[i][128 + d] = m;
      Dl[i][d] = dl;
    }
  }
  __syncthreads();
  int n = tid;
  float az[16], ar[16], ah[16];
  {
    float bz = zl_b[n], br = rl_b[n], bh = hl_b[n];
    #pragma unroll
    for (int i = 0; i < 16; ++i){ az[i] = bz; ar[i] = br; ah[i] = bh; }
  }
  for (int k = 0; k < 256; k += 4){
    u32 wzr[4]; u16 wh[4];
    #pragma unroll
    for (int q = 0; q < 4; ++q){ wzr[q] = zr_preT[(k+q)*HH + n]; wh[q] = h_preT[(k+q)*HH + n]; }
    float wz[4], wr[4], whf[4];
    #pragma unroll
    for (int q = 0; q < 4; ++q){ wz[q] = bflo(wzr[q]); wr[q] = bfhi(wzr[q]); whf[q] = bf1(wh[q]); }
    #pragma unroll
    for (int i = 0; i < 16; ++i){
      const float4 a = *(const float4*)&A[i][k];
      const float aa[4] = {a.x, a.y, a.z, a.w};
      #pragma unroll
      for (int q = 0; q < 4; ++q){
        az[i] += aa[q]*wz[q];
        ar[i] += aa[q]*wr[q];
        ah[i] += aa[q]*whf[q];
      }
    }
  }
  float g[16];
  {
    float bg = gh_b[n];
    #pragma unroll
    for (int i = 0; i < 16; ++i) g[i] = bg;
  }
  for (int k = 0; k < 128; k += 4){
    u16 wh[4];
    #pragma unroll
    for (int q = 0; q < 4; ++q) wh[q] = ghT[(k+q)*HH + n];
    float wf[4];
    #pragma unroll
    for (int q = 0; q < 4; ++q) wf[q] = bf1(wh[q]);
    #pragma unroll
    for (int i = 0; i < 16; ++i){
      const float4 a = *(const float4*)&Dl[i][k];
      const float aa[4] = {a.x, a.y, a.z, a.w};
      #pragma unroll
      for (int q = 0; q < 4; ++q) g[i] += aa[q]*wf[q];
    }
  }
  size_t base = (size_t)r0 * HH + n;
  #pragma unroll
  for (int i = 0; i < 16; ++i){
    size_t o = base + (size_t)i * HH;
    zpre[o] = az[i];
    rpre[o] = ar[i];
    hpre[o] = ah[i];
    dh[o]   = __expf(-fmaxf(g[i], 0.f));
  }
}

// Kernel 2: sequential recurrence. 256 blocks x 2 batch rows, thread owns h column n.
__global__ __launch_bounds__(256) void recurrent(
    const float* __restrict__ zpre, const float* __restrict__ rpre,
    const float* __restrict__ hpre, const float* __restrict__ dh,
    const u32* __restrict__ zr_recT, const u16* __restrict__ h_recT,
    u16* __restrict__ hout){
  __shared__ float hd_lds[2][256];
  __shared__ float rh_lds[2][256];
  int n  = threadIdx.x;
  int b0 = blockIdx.x * 2;
  float h0 = 0.f, h1 = 0.f;
  for (int t = 0; t < TT; ++t){
    size_t off = ((size_t)t*BB + b0)*HH + n;
    float d0 = dh[off], d1 = dh[off + HH];
    float hd0 = d0 * h0, hd1 = d1 * h1;
    hd_lds[0][n] = hd0; hd_lds[1][n] = hd1;
    float az0 = zpre[off], az1 = zpre[off + HH];
    float ar0 = rpre[off], ar1 = rpre[off + HH];
    float ap0 = hpre[off], ap1 = hpre[off + HH];
    __syncthreads();   // S1: hd visible
    for (int k = 0; k < 256; k += 8){
      u32 w[8];
      #pragma unroll
      for (int q = 0; q < 8; ++q) w[q] = zr_recT[(k+q)*HH + n];
      float4 a0l = *(const float4*)&hd_lds[0][k];
      float4 a0h = *(const float4*)&hd_lds[0][k+4];
      float4 a1l = *(const float4*)&hd_lds[1][k];
      float4 a1h = *(const float4*)&hd_lds[1][k+4];
      const float a0[8] = {a0l.x,a0l.y,a0l.z,a0l.w,a0h.x,a0h.y,a0h.z,a0h.w};
      const float a1[8] = {a1l.x,a1l.y,a1l.z,a1l.w,a1h.x,a1h.y,a1h.z,a1h.w};
      #pragma unroll
      for (int q = 0; q < 8; ++q){
        float wz = bflo(w[q]), wr = bfhi(w[q]);
        az0 += a0[q]*wz; az1 += a1[q]*wz;
        ar0 += a0[q]*wr; ar1 += a1[q]*wr;
      }
    }
    float z0 = sigm(az0), z1 = sigm(az1);
    float r0 = sigm(ar0), r1 = sigm(ar1);
    rh_lds[0][n] = r0 * hd0;
    rh_lds[1][n] = r1 * hd1;
    __syncthreads();   // S2: rh visible (also fences hd reads before next overwrite)
    float ac0 = ap0, ac1 = ap1;
    for (int k = 0; k < 256; k += 8){
      u16 w[8];
      #pragma unroll
      for (int q = 0; q < 8; ++q) w[q] = h_recT[(k+q)*HH + n];
      float4 a0l = *(const float4*)&rh_lds[0][k];
      float4 a0h = *(const float4*)&rh_lds[0][k+4];
      float4 a1l = *(const float4*)&rh_lds[1][k];
      float4 a1h = *(const float4*)&rh_lds[1][k+4];
      const float a0[8] = {a0l.x,a0l.y,a0l.z,a0l.w,a0h.x,a0h.y,a0h.z,a0h.w};
      const float a1[8] = {a1l.x,a1l.y,a1l.z,a1l.w,a1h.x,a1h.y,a1h.z,a1h.w};
      #pragma unroll
      for (int q = 0; q < 8; ++q){
        float wf = bf1(w[q]);
        ac0 += a0[q]*wf; ac1 += a1[q]*wf;
      }
    }
    float ht0 = tanh_fast(ac0), ht1 = tanh_fast(ac1);
    h0 = (1.f - z0)*hd0 + z0*ht0;
    h1 = (1.f - z1)*hd1 + z1*ht1;
    hout[off] = f2bf(h0);
    hout[off + HH] = f2bf(h1);
  }
}

// Kernel 3: out[b,t] = sigmoid(h[t,b,:] . fc_w + fc_b). One wave per row.
__global__ __launch_bounds__(256) void head(const u16* __restrict__ hout,
    const float* __restrict__ fc_w, const float* __restrict__ fc_b,
    float* __restrict__ out){
  int w = threadIdx.x >> 6, lane = threadIdx.x & 63;
  int rr = blockIdx.x * 4 + w;           // rr = t*BB + b
  const ushort4 hv = *(const ushort4*)&hout[(size_t)rr*HH + lane*4];
  const float4 fw = *(const float4*)&fc_w[lane*4];
  float s = bf1(hv.x)*fw.x + bf1(hv.y)*fw.y + bf1(hv.z)*fw.z + bf1(hv.w)*fw.w;
  #pragma unroll
  for (int o = 32; o >= 1; o >>= 1) s += __shfl_xor(s, o, 64);
  if (lane == 0){
    int t = rr >> 9, b = rr & 511;
    out[b*TT + t] = sigm(s + fc_b[0]);
  }
}

extern "C" void kernel_launch(void* const* d_in, const int* in_sizes, int n_in,
                              void* d_out, int out_size, void* d_ws, size_t ws_size,
                              hipStream_t stream) {
  const float* input = (const float*)d_in[0];
  const float* xmean = (const float*)d_in[1];
  const float* zl_w  = (const float*)d_in[2];
  const float* zl_b  = (const float*)d_in[3];
  const float* rl_w  = (const float*)d_in[4];
  const float* rl_b  = (const float*)d_in[5];
  const float* hl_w  = (const float*)d_in[6];
  const float* hl_b  = (const float*)d_in[7];
  const float* gx_w  = (const float*)d_in[8];
  const float* gx_b  = (const float*)d_in[9];
  const float* gh_w  = (const float*)d_in[10];
  const float* gh_b  = (const float*)d_in[11];
  const float* fc_w  = (const float*)d_in[12];
  const float* fc_b  = (const float*)d_in[13];
  float* out = (float*)d_out;

  const size_t S = (size_t)TT * BB * HH;   // 16,777,216 elements
  float* zpre = (float*)d_ws;
  float* rpre = zpre + S;
  float* hpre = rpre + S;
  float* dhp  = hpre + S;
  u16*   hout = (u16*)(dhp + S);
  u32*   zr_preT = (u32*)(hout + S);
  u16*   h_preT  = (u16*)(zr_preT + 65536);
  u32*   zr_recT = (u32*)(h_preT + 65536);
  u16*   h_recT  = (u16*)(zr_recT + 65536);
  u16*   ghT     = (u16*)(h_recT + 65536);

  prep_weights<<<256, 256, 0, stream>>>(zl_w, rl_w, hl_w, gh_w,
                                        zr_preT, h_preT, zr_recT, h_recT, ghT);
  precompute<<<4096, 256, 0, stream>>>(input, xmean, gx_w, gx_b,
                                       zl_b, rl_b, hl_b, gh_b,
                                       zr_preT, h_preT, ghT,
                                       zpre, rpre, hpre, dhp);
  recurrent<<<256, 256, 0, stream>>>(zpre, rpre, hpre, dhp, zr_recT, h_recT, hout);
  head<<<16384, 256, 0, stream>>>(hout, fc_w, fc_b, out);
}

// Round 6
// 1174.567 us; speedup vs baseline: 1.7057x; 1.7057x over previous
//
#include <hip/hip_runtime.h>
#include <hip/hip_bf16.h>
#include <cstdint>

typedef unsigned int u32;
typedef unsigned short u16;
typedef __attribute__((ext_vector_type(8))) short bf16x8;
typedef __attribute__((ext_vector_type(4))) float f32x4;

#define TT 128
#define BB 512
#define DD 128
#define HH 256
#define CC 512

// LDS map (u32 units): [0,32768) hl weights frag-ordered; [32768,34816) hd A-tile; [34816,36864) P A-tile
#define HDA_OFF 32768
#define PA_OFF  34816

__device__ __forceinline__ u16 f2bf(float f){
  u32 u = __builtin_bit_cast(u32, f);
  u += 0x7FFFu + ((u >> 16) & 1u);
  return (u16)(u >> 16);
}
__device__ __forceinline__ float bflo(u32 w){ return __builtin_bit_cast(float, w << 16); }
__device__ __forceinline__ float bfhi(u32 w){ return __builtin_bit_cast(float, w & 0xFFFF0000u); }
__device__ __forceinline__ float bf1(u16 w){ return __builtin_bit_cast(float, ((u32)w) << 16); }
__device__ __forceinline__ float sigm(float x){ return 1.f / (1.f + __expf(-x)); }
__device__ __forceinline__ float tanh_fast(float x){
  float t = __expf(-2.f * fabsf(x));
  float r = (1.f - t) / (1.f + t);
  return copysignf(r, x);
}

// Kernel 0: pack weights.
// (a) [k][n] bf16 arrays for precompute (unchanged layout).
// (b) MFMA fragment-ordered arrays for the recurrent kernel:
//     idx = ((ntg*8 + kt)*64 + l)*4 + d ; n = 16*ntg + (l&15) ; k = 32*kt + 8*(l>>4) + 2d(+1)
//     value = W[n][128+k]  (h-slice of combined), packed bf16 pair per u32.
__global__ void prep_weights(const float* __restrict__ zl_w, const float* __restrict__ rl_w,
                             const float* __restrict__ hl_w, const float* __restrict__ gh_w,
                             u32* __restrict__ zr_preT, u16* __restrict__ h_preT,
                             u16* __restrict__ ghT,
                             u32* __restrict__ zlB, u32* __restrict__ rlB, u32* __restrict__ hlF){
  int k = blockIdx.x;   // 0..255
  int n = threadIdx.x;  // 0..255
  int colp = (k < 128) ? k : (k + 256);
  zr_preT[k*HH + n] = (u32)f2bf(zl_w[n*CC + colp]) | ((u32)f2bf(rl_w[n*CC + colp]) << 16);
  h_preT[k*HH + n]  = f2bf(hl_w[n*CC + colp]);
  if (k < 128) ghT[k*HH + n] = f2bf(gh_w[n*DD + k]);

  int idx = blockIdx.x * 256 + threadIdx.x;
  if (idx < 32768){
    int d   = idx & 3;
    int l   = (idx >> 2) & 63;
    int kt  = (idx >> 8) & 7;
    int ntg = (idx >> 11) & 15;
    int nn  = 16*ntg + (l & 15);
    int kk  = 32*kt + 8*(l >> 4) + 2*d;
    int c0 = 128 + kk, c1 = 128 + kk + 1;
    zlB[idx] = (u32)f2bf(zl_w[nn*CC + c0]) | ((u32)f2bf(zl_w[nn*CC + c1]) << 16);
    rlB[idx] = (u32)f2bf(rl_w[nn*CC + c0]) | ((u32)f2bf(rl_w[nn*CC + c1]) << 16);
    hlF[idx] = (u32)f2bf(hl_w[nn*CC + c0]) | ((u32)f2bf(hl_w[nn*CC + c1]) << 16);
  }
}

// Kernel 1: precompute z_pre/r_pre/h_pre (K=256 GEMM) and delta_h (K=128 GEMM) for all (t,b).
__global__ __launch_bounds__(256) void precompute(
    const float* __restrict__ input, const float* __restrict__ xmean,
    const float* __restrict__ gx_w, const float* __restrict__ gx_b,
    const float* __restrict__ zl_b, const float* __restrict__ rl_b,
    const float* __restrict__ hl_b, const float* __restrict__ gh_b,
    const u32* __restrict__ zr_preT, const u16* __restrict__ h_preT, const u16* __restrict__ ghT,
    float* __restrict__ zpre, float* __restrict__ rpre, float* __restrict__ hpre,
    float* __restrict__ dh){
  __shared__ float A[16][260];
  __shared__ float Dl[16][132];
  int r0 = blockIdx.x * 16;
  int t  = r0 >> 9;
  int b0 = r0 & 511;
  int tid = threadIdx.x;
  {
    int i = tid >> 4, j = tid & 15;
    int b = b0 + i, d0 = j * 8;
    const float* px  = input + (((size_t)(b*4 + 0)*TT + t)*DD + d0);
    const float* pxl = input + (((size_t)(b*4 + 1)*TT + t)*DD + d0);
    const float* pm  = input + (((size_t)(b*4 + 2)*TT + t)*DD + d0);
    const float* pd  = input + (((size_t)(b*4 + 3)*TT + t)*DD + d0);
    const float* pxm = xmean + t*DD + d0;
    #pragma unroll
    for (int jj = 0; jj < 8; ++jj){
      int d = d0 + jj;
      float x = px[jj], xl = pxl[jj], m = pm[jj], dl = pd[jj];
      float dxv = __expf(-fmaxf(dl * gx_w[d*DD + d] + gx_b[d], 0.f));
      float xe  = m*x + (1.f - m)*(dxv*xl + (1.f - dxv)*pxm[jj]);
      A[i][d] = xe;
      A[i][128 + d] = m;
      Dl[i][d] = dl;
    }
  }
  __syncthreads();
  int n = tid;
  float az[16], ar[16], ah[16];
  {
    float bz = zl_b[n], br = rl_b[n], bh = hl_b[n];
    #pragma unroll
    for (int i = 0; i < 16; ++i){ az[i] = bz; ar[i] = br; ah[i] = bh; }
  }
  for (int k = 0; k < 256; k += 4){
    u32 wzr[4]; u16 wh[4];
    #pragma unroll
    for (int q = 0; q < 4; ++q){ wzr[q] = zr_preT[(k+q)*HH + n]; wh[q] = h_preT[(k+q)*HH + n]; }
    float wz[4], wr[4], whf[4];
    #pragma unroll
    for (int q = 0; q < 4; ++q){ wz[q] = bflo(wzr[q]); wr[q] = bfhi(wzr[q]); whf[q] = bf1(wh[q]); }
    #pragma unroll
    for (int i = 0; i < 16; ++i){
      const float4 a = *(const float4*)&A[i][k];
      const float aa[4] = {a.x, a.y, a.z, a.w};
      #pragma unroll
      for (int q = 0; q < 4; ++q){
        az[i] += aa[q]*wz[q];
        ar[i] += aa[q]*wr[q];
        ah[i] += aa[q]*whf[q];
      }
    }
  }
  float g[16];
  {
    float bg = gh_b[n];
    #pragma unroll
    for (int i = 0; i < 16; ++i) g[i] = bg;
  }
  for (int k = 0; k < 128; k += 4){
    u16 wh[4];
    #pragma unroll
    for (int q = 0; q < 4; ++q) wh[q] = ghT[(k+q)*HH + n];
    float wf[4];
    #pragma unroll
    for (int q = 0; q < 4; ++q) wf[q] = bf1(wh[q]);
    #pragma unroll
    for (int i = 0; i < 16; ++i){
      const float4 a = *(const float4*)&Dl[i][k];
      const float aa[4] = {a.x, a.y, a.z, a.w};
      #pragma unroll
      for (int q = 0; q < 4; ++q) g[i] += aa[q]*wf[q];
    }
  }
  size_t base = (size_t)r0 * HH + n;
  #pragma unroll
  for (int i = 0; i < 16; ++i){
    size_t o = base + (size_t)i * HH;
    zpre[o] = az[i];
    rpre[o] = ar[i];
    hpre[o] = ah[i];
    dh[o]   = __expf(-fmaxf(g[i], 0.f));
  }
}

// Kernel 2: MFMA recurrence. grid=32 blocks x 16 batch rows; 8 waves; wave w owns h-cols [32w,32w+32).
// zl/rl B-fragments resident in VGPRs; hl weights resident in LDS (frag-ordered).
// Per step: zr GEMM (32 mfma/wave) -> sigm -> P=r*hd to LDS -> bar -> htilde GEMM (16 mfma/wave)
// -> tanh/combine -> write hd(t+1) to LDS + hout -> bar.
__global__ __launch_bounds__(512, 2) void recurrent_mfma(
    const float* __restrict__ zpre, const float* __restrict__ rpre,
    const float* __restrict__ hpre, const float* __restrict__ dh,
    const u32* __restrict__ zlB, const u32* __restrict__ rlB,
    const u32* __restrict__ hlF, u16* __restrict__ hout){
  __shared__ u32 smem[36864];   // 144 KB
  const int tid = threadIdx.x;
  const int l = tid & 63, w = tid >> 6;
  const int b0 = blockIdx.x * 16;
  const int rowb = 4 * (l >> 4);          // C/D row base; + jr
  const int col0 = 32*w + (l & 15);       // nt=0 col; nt=1 is +16

  // stage hl weights into LDS (coalesced), zero hd A-tile
  #pragma unroll
  for (int i = 0; i < 64; ++i) smem[i*512 + tid] = hlF[i*512 + tid];
  #pragma unroll
  for (int i = 0; i < 4; ++i) smem[HDA_OFF + i*512 + tid] = 0;

  // zl/rl B-fragments -> registers (held across all 128 steps)
  bf16x8 zb[2][8], rb[2][8];
  #pragma unroll
  for (int nt = 0; nt < 2; ++nt){
    #pragma unroll
    for (int kt = 0; kt < 8; ++kt){
      int off = (((w*2 + nt)*8 + kt)*64 + l)*4;
      zb[nt][kt] = *(const bf16x8*)(zlB + off);
      rb[nt][kt] = *(const bf16x8*)(rlB + off);
    }
  }
  __syncthreads();

  // scatter base (u16 index) for writing element (row, k=col) into an A-tile:
  // idx = ktile*512 + lane'*8 + j ; lane' = row + 16*(2nt + ((l>>3)&1)) ; j = l&7 ; ktile = w
  int scb[2];
  #pragma unroll
  for (int nt = 0; nt < 2; ++nt)
    scb[nt] = w*512 + (2*nt + ((l >> 3) & 1))*128 + rowb*8 + (l & 7);

  float hdreg[2][4] = {{0.f,0.f,0.f,0.f},{0.f,0.f,0.f,0.f}};
  float zreg[2][4];

  u16* pa16 = (u16*)(smem + PA_OFF);
  u16* hd16 = (u16*)(smem + HDA_OFF);

  for (int t = 0; t < TT; ++t){
    // global preloads for this step (+ dh for next step)
    float pz[2][4], pr[2][4], ph[2][4], pdh[2][4];
    int tn = (t < TT-1) ? t+1 : TT-1;
    #pragma unroll
    for (int nt = 0; nt < 2; ++nt){
      #pragma unroll
      for (int jr = 0; jr < 4; ++jr){
        size_t o  = ((size_t)t *BB + b0 + rowb + jr)*HH + col0 + 16*nt;
        size_t o2 = ((size_t)tn*BB + b0 + rowb + jr)*HH + col0 + 16*nt;
        pz[nt][jr]  = zpre[o];
        pr[nt][jr]  = rpre[o];
        ph[nt][jr]  = hpre[o];
        pdh[nt][jr] = dh[o2];
      }
    }
    // zr GEMM: C += hd(t) x W
    f32x4 cz[2] = {{0.f,0.f,0.f,0.f},{0.f,0.f,0.f,0.f}};
    f32x4 cr[2] = {{0.f,0.f,0.f,0.f},{0.f,0.f,0.f,0.f}};
    #pragma unroll
    for (int kt = 0; kt < 8; ++kt){
      bf16x8 a = *(const bf16x8*)(smem + HDA_OFF + kt*256 + l*4);
      cz[0] = __builtin_amdgcn_mfma_f32_16x16x32_bf16(a, zb[0][kt], cz[0], 0, 0, 0);
      cz[1] = __builtin_amdgcn_mfma_f32_16x16x32_bf16(a, zb[1][kt], cz[1], 0, 0, 0);
      cr[0] = __builtin_amdgcn_mfma_f32_16x16x32_bf16(a, rb[0][kt], cr[0], 0, 0, 0);
      cr[1] = __builtin_amdgcn_mfma_f32_16x16x32_bf16(a, rb[1][kt], cr[1], 0, 0, 0);
    }
    // gates; write P = r*hd fragments
    #pragma unroll
    for (int nt = 0; nt < 2; ++nt){
      #pragma unroll
      for (int jr = 0; jr < 4; ++jr){
        float zv = sigm(pz[nt][jr] + cz[nt][jr]);
        float rv = sigm(pr[nt][jr] + cr[nt][jr]);
        zreg[nt][jr] = zv;
        pa16[scb[nt] + jr*8] = f2bf(rv * hdreg[nt][jr]);
      }
    }
    __syncthreads();   // P visible; all zr reads of hd(t) complete
    // htilde GEMM: C += P x Whl (B from LDS)
    f32x4 ch[2] = {{0.f,0.f,0.f,0.f},{0.f,0.f,0.f,0.f}};
    #pragma unroll
    for (int kt = 0; kt < 8; ++kt){
      bf16x8 a  = *(const bf16x8*)(smem + PA_OFF + kt*256 + l*4);
      bf16x8 bh0 = *(const bf16x8*)(smem + ((2*w+0)*8 + kt)*256 + l*4);
      bf16x8 bh1 = *(const bf16x8*)(smem + ((2*w+1)*8 + kt)*256 + l*4);
      ch[0] = __builtin_amdgcn_mfma_f32_16x16x32_bf16(a, bh0, ch[0], 0, 0, 0);
      ch[1] = __builtin_amdgcn_mfma_f32_16x16x32_bf16(a, bh1, ch[1], 0, 0, 0);
    }
    // combine, emit h, stage hd(t+1)
    #pragma unroll
    for (int nt = 0; nt < 2; ++nt){
      #pragma unroll
      for (int jr = 0; jr < 4; ++jr){
        float ht = tanh_fast(ph[nt][jr] + ch[nt][jr]);
        float hd = hdreg[nt][jr];
        float zv = zreg[nt][jr];
        float hn = (1.f - zv)*hd + zv*ht;
        size_t o = ((size_t)t*BB + b0 + rowb + jr)*HH + col0 + 16*nt;
        hout[o] = f2bf(hn);
        float hdn = pdh[nt][jr] * hn;
        hdreg[nt][jr] = hdn;
        hd16[scb[nt] + jr*8] = f2bf(hdn);
      }
    }
    __syncthreads();   // hd(t+1) ready; P reads complete
  }
}

// Kernel 3: out[b,t] = sigmoid(h[t,b,:] . fc_w + fc_b). One wave per row.
__global__ __launch_bounds__(256) void head(const u16* __restrict__ hout,
    const float* __restrict__ fc_w, const float* __restrict__ fc_b,
    float* __restrict__ out){
  int w = threadIdx.x >> 6, lane = threadIdx.x & 63;
  int rr = blockIdx.x * 4 + w;           // rr = t*BB + b
  const ushort4 hv = *(const ushort4*)&hout[(size_t)rr*HH + lane*4];
  const float4 fw = *(const float4*)&fc_w[lane*4];
  float s = bf1(hv.x)*fw.x + bf1(hv.y)*fw.y + bf1(hv.z)*fw.z + bf1(hv.w)*fw.w;
  #pragma unroll
  for (int o = 32; o >= 1; o >>= 1) s += __shfl_xor(s, o, 64);
  if (lane == 0){
    int t = rr >> 9, b = rr & 511;
    out[b*TT + t] = sigm(s + fc_b[0]);
  }
}

extern "C" void kernel_launch(void* const* d_in, const int* in_sizes, int n_in,
                              void* d_out, int out_size, void* d_ws, size_t ws_size,
                              hipStream_t stream) {
  const float* input = (const float*)d_in[0];
  const float* xmean = (const float*)d_in[1];
  const float* zl_w  = (const float*)d_in[2];
  const float* zl_b  = (const float*)d_in[3];
  const float* rl_w  = (const float*)d_in[4];
  const float* rl_b  = (const float*)d_in[5];
  const float* hl_w  = (const float*)d_in[6];
  const float* hl_b  = (const float*)d_in[7];
  const float* gx_w  = (const float*)d_in[8];
  const float* gx_b  = (const float*)d_in[9];
  const float* gh_w  = (const float*)d_in[10];
  const float* gh_b  = (const float*)d_in[11];
  const float* fc_w  = (const float*)d_in[12];
  const float* fc_b  = (const float*)d_in[13];
  float* out = (float*)d_out;

  const size_t S = (size_t)TT * BB * HH;   // 16,777,216
  float* zpre = (float*)d_ws;
  float* rpre = zpre + S;
  float* hpre = rpre + S;
  float* dhp  = hpre + S;
  u16*   hout = (u16*)(dhp + S);
  u32*   zr_preT = (u32*)(hout + S);
  u16*   h_preT  = (u16*)(zr_preT + 65536);
  u16*   ghT     = h_preT + 65536;
  u32*   zlB     = (u32*)(ghT + 32768);
  u32*   rlB     = zlB + 32768;
  u32*   hlF     = rlB + 32768;

  prep_weights<<<256, 256, 0, stream>>>(zl_w, rl_w, hl_w, gh_w,
                                        zr_preT, h_preT, ghT, zlB, rlB, hlF);
  precompute<<<4096, 256, 0, stream>>>(input, xmean, gx_w, gx_b,
                                       zl_b, rl_b, hl_b, gh_b,
                                       zr_preT, h_preT, ghT,
                                       zpre, rpre, hpre, dhp);
  recurrent_mfma<<<32, 512, 0, stream>>>(zpre, rpre, hpre, dhp, zlB, rlB, hlF, hout);
  head<<<16384, 256, 0, stream>>>(hout, fc_w, fc_b, out);
}

// Round 7
// 887.737 us; speedup vs baseline: 2.2569x; 1.3231x over previous
//
#include <hip/hip_runtime.h>
#include <hip/hip_bf16.h>
#include <cstdint>

typedef unsigned int u32;
typedef unsigned short u16;
typedef __attribute__((ext_vector_type(8))) short bf16x8;
typedef __attribute__((ext_vector_type(4))) float f32x4;

#define TT 128
#define BB 512
#define DD 128
#define HH 256
#define CC 512

// recurrent LDS map (u32 units)
#define HDA_OFF 32768
#define PA_OFF  34816

// raw barrier: LDS ordering only — do NOT drain vmcnt (hout stores / preloads stay in flight)
#define BAR() do { asm volatile("s_waitcnt lgkmcnt(0)" ::: "memory"); \
                   __builtin_amdgcn_s_barrier(); \
                   asm volatile("" ::: "memory"); } while(0)

__device__ __forceinline__ u16 f2bf(float f){
  u32 u = __builtin_bit_cast(u32, f);
  u += 0x7FFFu + ((u >> 16) & 1u);
  return (u16)(u >> 16);
}
__device__ __forceinline__ float bf1(u16 w){ return __builtin_bit_cast(float, ((u32)w) << 16); }
__device__ __forceinline__ float sigm(float x){ return 1.f / (1.f + __expf(-x)); }
__device__ __forceinline__ float tanh_fast(float x){
  float t = __expf(-2.f * fabsf(x));
  float r = (1.f - t) / (1.f + t);
  return copysignf(r, x);
}

// Kernel 0: pack weights.
// zlB/rlB/hlF: recurrent B-frags (validated layout): idx=((ntg*8+kt)*64+l)*4+d ;
//   n=16ntg+(l&15); k=32kt+8(l>>4)+2d(+1); value=W[n][128+k] (h-slice).
// Bpre [48nt][8kt][64][4]: fused z(nt0-15)/r(16-31)/h(32-47) pre-GEMM B; A-k 0-127 -> col k (x),
//   128-255 -> col k+256 (m). ghF [16nt][4kt][64][4]: gh_w B. gxd: diag(gx_w).
__global__ __launch_bounds__(256) void prep_weights(
    const float* __restrict__ zl_w, const float* __restrict__ rl_w,
    const float* __restrict__ hl_w, const float* __restrict__ gh_w,
    const float* __restrict__ gx_w,
    u32* __restrict__ zlB, u32* __restrict__ rlB, u32* __restrict__ hlF,
    u32* __restrict__ Bpre, u32* __restrict__ ghF, float* __restrict__ gxd){
  int gid = blockIdx.x * 256 + threadIdx.x;   // 0..65535
  if (gid < 32768){
    int d   = gid & 3;
    int l   = (gid >> 2) & 63;
    int kt  = (gid >> 8) & 7;
    int ntg = (gid >> 11) & 15;
    int nn  = 16*ntg + (l & 15);
    int kk  = 32*kt + 8*(l >> 4) + 2*d;
    int c0 = 128 + kk;
    zlB[gid] = (u32)f2bf(zl_w[nn*CC + c0]) | ((u32)f2bf(zl_w[nn*CC + c0 + 1]) << 16);
    rlB[gid] = (u32)f2bf(rl_w[nn*CC + c0]) | ((u32)f2bf(rl_w[nn*CC + c0 + 1]) << 16);
    hlF[gid] = (u32)f2bf(hl_w[nn*CC + c0]) | ((u32)f2bf(hl_w[nn*CC + c0 + 1]) << 16);
  }
  #pragma unroll
  for (int q = 0; q < 2; ++q){
    int id = q*65536 + gid;
    if (id < 98304){
      int d2 = id & 3;
      int l  = (id >> 2) & 63;
      int kt = (id >> 8) & 7;
      int nt = id >> 11;            // 0..47
      int g  = nt >> 4;
      int nc = (nt & 15)*16 + (l & 15);
      int k  = 32*kt + 8*(l >> 4) + 2*d2;
      int sc = (k < 128) ? k : k + 256;
      const float* W = (g == 0) ? zl_w : ((g == 1) ? rl_w : hl_w);
      Bpre[id] = (u32)f2bf(W[nc*CC + sc]) | ((u32)f2bf(W[nc*CC + sc + 1]) << 16);
    }
  }
  if (gid < 16384){
    int d2 = gid & 3;
    int l  = (gid >> 2) & 63;
    int kt = (gid >> 8) & 3;
    int nt = gid >> 10;             // 0..15
    int nc = nt*16 + (l & 15);
    int k  = 32*kt + 8*(l >> 4) + 2*d2;
    ghF[gid] = (u32)f2bf(gh_w[nc*DD + k]) | ((u32)f2bf(gh_w[nc*DD + k + 1]) << 16);
  }
  if (gid < 128) gxd[gid] = gx_w[gid*DD + gid];
}

// Kernel 1: MFMA precompute. Block = 64 rows (one t), 512 thr = 8 waves (2M x 4N).
// Prologue: x_eff/m -> A1 (K=256 frag-order), delta -> A2 (K=128). Phase1: A1 x Bpre (N=768)
// -> zpre/rpre/hpre (+bias, f32). Phase2: A2 x ghF (N=256) -> dh = exp(-relu(.+bias)).
__global__ __launch_bounds__(512, 2) void precompute_mfma(
    const float* __restrict__ input, const float* __restrict__ xmean,
    const float* __restrict__ gxd, const float* __restrict__ gx_b,
    const float* __restrict__ zl_b, const float* __restrict__ rl_b,
    const float* __restrict__ hl_b, const float* __restrict__ gh_b,
    const u32* __restrict__ Bpre, const u32* __restrict__ ghF,
    float* __restrict__ zpre, float* __restrict__ rpre, float* __restrict__ hpre,
    float* __restrict__ dh){
  __shared__ __align__(16) u16 A1[4][8][64][8];   // 32 KB [mt][kt][lane][j]
  __shared__ __align__(16) u16 A2[4][4][64][8];   // 16 KB
  const int tid = threadIdx.x;
  const int r0 = blockIdx.x * 64;
  const int t  = r0 >> 9;
  const int b0 = r0 & 511;
  // ---- prologue: 8 threads/row x 16 d each
  {
    int row = tid >> 3, dsg = tid & 7, d0 = dsg * 16;
    int b = b0 + row;
    const size_t ib = ((size_t)b * 4 * TT + t) * DD;   // channel stride TT*DD
    int mt = row >> 4;
    #pragma unroll
    for (int gg = 0; gg < 2; ++gg){
      int db = d0 + 8*gg;
      float xv[8], lv[8], mv[8], dv[8], xm[8], gd[8], gb[8];
      #pragma unroll
      for (int q = 0; q < 2; ++q){
        *(float4*)&xv[q*4] = *(const float4*)&input[ib + 0*TT*DD + db + q*4];
        *(float4*)&lv[q*4] = *(const float4*)&input[ib + 1*TT*DD + db + q*4];
        *(float4*)&mv[q*4] = *(const float4*)&input[ib + 2*TT*DD + db + q*4];
        *(float4*)&dv[q*4] = *(const float4*)&input[ib + 3*TT*DD + db + q*4];
        *(float4*)&xm[q*4] = *(const float4*)&xmean[t*DD + db + q*4];
        *(float4*)&gd[q*4] = *(const float4*)&gxd[db + q*4];
        *(float4*)&gb[q*4] = *(const float4*)&gx_b[db + q*4];
      }
      union { u16 s[8]; bf16x8 v; } pe, pm, pd;
      #pragma unroll
      for (int j = 0; j < 8; ++j){
        float dxv = __expf(-fmaxf(dv[j]*gd[j] + gb[j], 0.f));
        float xe  = mv[j]*xv[j] + (1.f - mv[j])*(dxv*lv[j] + (1.f - dxv)*xm[j]);
        pe.s[j] = f2bf(xe);
        pm.s[j] = f2bf(mv[j]);
        pd.s[j] = f2bf(dv[j]);
      }
      int kt1 = db >> 5;
      int l1  = (row & 15) + 16*((db >> 3) & 3);
      *(bf16x8*)&A1[mt][kt1][l1][0]     = pe.v;
      *(bf16x8*)&A1[mt][4 + kt1][l1][0] = pm.v;
      *(bf16x8*)&A2[mt][kt1][l1][0]     = pd.v;
    }
  }
  __syncthreads();
  const int l = tid & 63, w = tid >> 6;
  const int wm = w >> 2, wn = w & 3;
  const int rowl = 4 * (l >> 4), coll = l & 15;
  // ---- phase 1: K=256, wave covers 32 rows x 192 cols
  f32x4 acc[2][12];
  #pragma unroll
  for (int m = 0; m < 2; ++m)
    #pragma unroll
    for (int i = 0; i < 12; ++i) acc[m][i] = (f32x4){0.f,0.f,0.f,0.f};
  #pragma unroll
  for (int kt = 0; kt < 8; ++kt){
    bf16x8 a0 = *(const bf16x8*)&A1[wm*2 + 0][kt][l][0];
    bf16x8 a1 = *(const bf16x8*)&A1[wm*2 + 1][kt][l][0];
    #pragma unroll
    for (int i = 0; i < 12; ++i){
      int nt = wn*12 + i;
      bf16x8 bf = *(const bf16x8*)(Bpre + ((nt*8 + kt)*64 + l)*4);
      acc[0][i] = __builtin_amdgcn_mfma_f32_16x16x32_bf16(a0, bf, acc[0][i], 0, 0, 0);
      acc[1][i] = __builtin_amdgcn_mfma_f32_16x16x32_bf16(a1, bf, acc[1][i], 0, 0, 0);
    }
  }
  #pragma unroll
  for (int m = 0; m < 2; ++m){
    int grow = r0 + wm*32 + m*16 + rowl;
    #pragma unroll
    for (int i = 0; i < 12; ++i){
      int nt = wn*12 + i;
      int g = nt >> 4;
      int lc = (nt & 15)*16 + coll;
      float bias; float* dst;
      if (g == 0){ dst = zpre; bias = zl_b[lc]; }
      else if (g == 1){ dst = rpre; bias = rl_b[lc]; }
      else { dst = hpre; bias = hl_b[lc]; }
      #pragma unroll
      for (int rg = 0; rg < 4; ++rg)
        dst[(size_t)(grow + rg)*HH + lc] = acc[m][i][rg] + bias;
    }
  }
  // ---- phase 2: K=128, dh
  f32x4 ac2[2][4];
  #pragma unroll
  for (int m = 0; m < 2; ++m)
    #pragma unroll
    for (int i = 0; i < 4; ++i) ac2[m][i] = (f32x4){0.f,0.f,0.f,0.f};
  #pragma unroll
  for (int kt = 0; kt < 4; ++kt){
    bf16x8 a0 = *(const bf16x8*)&A2[wm*2 + 0][kt][l][0];
    bf16x8 a1 = *(const bf16x8*)&A2[wm*2 + 1][kt][l][0];
    #pragma unroll
    for (int i = 0; i < 4; ++i){
      int nt = wn*4 + i;
      bf16x8 bf = *(const bf16x8*)(ghF + ((nt*4 + kt)*64 + l)*4);
      ac2[0][i] = __builtin_amdgcn_mfma_f32_16x16x32_bf16(a0, bf, ac2[0][i], 0, 0, 0);
      ac2[1][i] = __builtin_amdgcn_mfma_f32_16x16x32_bf16(a1, bf, ac2[1][i], 0, 0, 0);
    }
  }
  #pragma unroll
  for (int m = 0; m < 2; ++m){
    int grow = r0 + wm*32 + m*16 + rowl;
    #pragma unroll
    for (int i = 0; i < 4; ++i){
      int lc = (wn*4 + i)*16 + coll;
      float bias = gh_b[lc];
      #pragma unroll
      for (int rg = 0; rg < 4; ++rg)
        dh[(size_t)(grow + rg)*HH + lc] = __expf(-fmaxf(ac2[m][i][rg] + bias, 0.f));
    }
  }
}

// Kernel 2: MFMA recurrence (validated). grid=32 x 16 rows; 8 waves; wave w: h-cols [32w,32w+32).
// Raw barriers: only lgkmcnt(0) — hout stores & next-step loads stay in flight across steps.
__global__ __launch_bounds__(512, 2) void recurrent_mfma(
    const float* __restrict__ zpre, const float* __restrict__ rpre,
    const float* __restrict__ hpre, const float* __restrict__ dh,
    const u32* __restrict__ zlB, const u32* __restrict__ rlB,
    const u32* __restrict__ hlF, u16* __restrict__ hout){
  __shared__ u32 smem[36864];   // 144 KB
  const int tid = threadIdx.x;
  const int l = tid & 63, w = tid >> 6;
  const int b0 = blockIdx.x * 16;
  const int rowb = 4 * (l >> 4);
  const int col0 = 32*w + (l & 15);

  #pragma unroll
  for (int i = 0; i < 64; ++i) smem[i*512 + tid] = hlF[i*512 + tid];
  #pragma unroll
  for (int i = 0; i < 4; ++i) smem[HDA_OFF + i*512 + tid] = 0;

  bf16x8 zb[2][8], rb[2][8];
  #pragma unroll
  for (int nt = 0; nt < 2; ++nt){
    #pragma unroll
    for (int kt = 0; kt < 8; ++kt){
      int off = (((w*2 + nt)*8 + kt)*64 + l)*4;
      zb[nt][kt] = *(const bf16x8*)(zlB + off);
      rb[nt][kt] = *(const bf16x8*)(rlB + off);
    }
  }
  __syncthreads();

  int scb[2];
  #pragma unroll
  for (int nt = 0; nt < 2; ++nt)
    scb[nt] = w*512 + (2*nt + ((l >> 3) & 1))*128 + rowb*8 + (l & 7);

  float hdreg[2][4] = {{0.f,0.f,0.f,0.f},{0.f,0.f,0.f,0.f}};
  float zreg[2][4];

  u16* pa16 = (u16*)(smem + PA_OFF);
  u16* hd16 = (u16*)(smem + HDA_OFF);

  for (int t = 0; t < TT; ++t){
    float pz[2][4], pr[2][4], ph[2][4], pdh[2][4];
    int tn = (t < TT-1) ? t+1 : TT-1;
    #pragma unroll
    for (int nt = 0; nt < 2; ++nt){
      #pragma unroll
      for (int jr = 0; jr < 4; ++jr){
        size_t o  = ((size_t)t *BB + b0 + rowb + jr)*HH + col0 + 16*nt;
        size_t o2 = ((size_t)tn*BB + b0 + rowb + jr)*HH + col0 + 16*nt;
        pz[nt][jr]  = zpre[o];
        pr[nt][jr]  = rpre[o];
        ph[nt][jr]  = hpre[o];
        pdh[nt][jr] = dh[o2];
      }
    }
    f32x4 cz[2] = {{0.f,0.f,0.f,0.f},{0.f,0.f,0.f,0.f}};
    f32x4 cr[2] = {{0.f,0.f,0.f,0.f},{0.f,0.f,0.f,0.f}};
    #pragma unroll
    for (int kt = 0; kt < 8; ++kt){
      bf16x8 a = *(const bf16x8*)(smem + HDA_OFF + kt*256 + l*4);
      cz[0] = __builtin_amdgcn_mfma_f32_16x16x32_bf16(a, zb[0][kt], cz[0], 0, 0, 0);
      cz[1] = __builtin_amdgcn_mfma_f32_16x16x32_bf16(a, zb[1][kt], cz[1], 0, 0, 0);
      cr[0] = __builtin_amdgcn_mfma_f32_16x16x32_bf16(a, rb[0][kt], cr[0], 0, 0, 0);
      cr[1] = __builtin_amdgcn_mfma_f32_16x16x32_bf16(a, rb[1][kt], cr[1], 0, 0, 0);
    }
    #pragma unroll
    for (int nt = 0; nt < 2; ++nt){
      #pragma unroll
      for (int jr = 0; jr < 4; ++jr){
        float zv = sigm(pz[nt][jr] + cz[nt][jr]);
        float rv = sigm(pr[nt][jr] + cr[nt][jr]);
        zreg[nt][jr] = zv;
        pa16[scb[nt] + jr*8] = f2bf(rv * hdreg[nt][jr]);
      }
    }
    BAR();   // S1: P visible; hd(t) reads drained (lgkm only)
    f32x4 ch[2] = {{0.f,0.f,0.f,0.f},{0.f,0.f,0.f,0.f}};
    #pragma unroll
    for (int kt = 0; kt < 8; ++kt){
      bf16x8 a  = *(const bf16x8*)(smem + PA_OFF + kt*256 + l*4);
      bf16x8 bh0 = *(const bf16x8*)(smem + ((2*w+0)*8 + kt)*256 + l*4);
      bf16x8 bh1 = *(const bf16x8*)(smem + ((2*w+1)*8 + kt)*256 + l*4);
      ch[0] = __builtin_amdgcn_mfma_f32_16x16x32_bf16(a, bh0, ch[0], 0, 0, 0);
      ch[1] = __builtin_amdgcn_mfma_f32_16x16x32_bf16(a, bh1, ch[1], 0, 0, 0);
    }
    #pragma unroll
    for (int nt = 0; nt < 2; ++nt){
      #pragma unroll
      for (int jr = 0; jr < 4; ++jr){
        float ht = tanh_fast(ph[nt][jr] + ch[nt][jr]);
        float hd = hdreg[nt][jr];
        float zv = zreg[nt][jr];
        float hn = (1.f - zv)*hd + zv*ht;
        size_t o = ((size_t)t*BB + b0 + rowb + jr)*HH + col0 + 16*nt;
        hout[o] = f2bf(hn);
        float hdn = pdh[nt][jr] * hn;
        hdreg[nt][jr] = hdn;
        hd16[scb[nt] + jr*8] = f2bf(hdn);
      }
    }
    BAR();   // S2: hd(t+1) visible; P reads drained (lgkm only)
  }
}

// Kernel 3: out[b,t] = sigmoid(h[t,b,:] . fc_w + fc_b). One wave per row.
__global__ __launch_bounds__(256) void head(const u16* __restrict__ hout,
    const float* __restrict__ fc_w, const float* __restrict__ fc_b,
    float* __restrict__ out){
  int w = threadIdx.x >> 6, lane = threadIdx.x & 63;
  int rr = blockIdx.x * 4 + w;           // rr = t*BB + b
  const ushort4 hv = *(const ushort4*)&hout[(size_t)rr*HH + lane*4];
  const float4 fw = *(const float4*)&fc_w[lane*4];
  float s = bf1(hv.x)*fw.x + bf1(hv.y)*fw.y + bf1(hv.z)*fw.z + bf1(hv.w)*fw.w;
  #pragma unroll
  for (int o = 32; o >= 1; o >>= 1) s += __shfl_xor(s, o, 64);
  if (lane == 0){
    int t = rr >> 9, b = rr & 511;
    out[b*TT + t] = sigm(s + fc_b[0]);
  }
}

extern "C" void kernel_launch(void* const* d_in, const int* in_sizes, int n_in,
                              void* d_out, int out_size, void* d_ws, size_t ws_size,
                              hipStream_t stream) {
  const float* input = (const float*)d_in[0];
  const float* xmean = (const float*)d_in[1];
  const float* zl_w  = (const float*)d_in[2];
  const float* zl_b  = (const float*)d_in[3];
  const float* rl_w  = (const float*)d_in[4];
  const float* rl_b  = (const float*)d_in[5];
  const float* hl_w  = (const float*)d_in[6];
  const float* hl_b  = (const float*)d_in[7];
  const float* gx_w  = (const float*)d_in[8];
  const float* gx_b  = (const float*)d_in[9];
  const float* gh_w  = (const float*)d_in[10];
  const float* gh_b  = (const float*)d_in[11];
  const float* fc_w  = (const float*)d_in[12];
  const float* fc_b  = (const float*)d_in[13];
  float* out = (float*)d_out;

  const size_t S = (size_t)TT * BB * HH;   // 16,777,216
  float* zpre = (float*)d_ws;
  float* rpre = zpre + S;
  float* hpre = rpre + S;
  float* dhp  = hpre + S;
  u16*   hout = (u16*)(dhp + S);
  u32*   zlB  = (u32*)(hout + S);
  u32*   rlB  = zlB + 32768;
  u32*   hlF  = rlB + 32768;
  u32*   Bpre = hlF + 32768;
  u32*   ghF  = Bpre + 98304;
  float* gxd  = (float*)(ghF + 16384);

  prep_weights<<<256, 256, 0, stream>>>(zl_w, rl_w, hl_w, gh_w, gx_w,
                                        zlB, rlB, hlF, Bpre, ghF, gxd);
  precompute_mfma<<<1024, 512, 0, stream>>>(input, xmean, gxd, gx_b,
                                            zl_b, rl_b, hl_b, gh_b,
                                            Bpre, ghF,
                                            zpre, rpre, hpre, dhp);
  recurrent_mfma<<<32, 512, 0, stream>>>(zpre, rpre, hpre, dhp, zlB, rlB, hlF, hout);
  head<<<16384, 256, 0, stream>>>(hout, fc_w, fc_b, out);
}

// Round 9
// 753.840 us; speedup vs baseline: 2.6577x; 1.1776x over previous
//
#include <hip/hip_runtime.h>
#include <hip/hip_bf16.h>
#include <cstdint>

typedef unsigned int u32;
typedef unsigned short u16;
typedef __attribute__((ext_vector_type(8))) short bf16x8;
typedef __attribute__((ext_vector_type(4))) float f32x4;

#define TT 128
#define BB 512
#define DD 128
#define HH 256
#define CC 512

// recurrent LDS map (u32 units)
#define HDA_OFF 32768
#define PA_OFF  34816

// raw barrier: LDS ordering only — do NOT drain vmcnt (stores/prefetch stay in flight)
#define BAR() do { asm volatile("s_waitcnt lgkmcnt(0)" ::: "memory"); \
                   __builtin_amdgcn_s_barrier(); \
                   asm volatile("" ::: "memory"); } while(0)

__device__ __forceinline__ u16 f2bf(float f){
  u32 u = __builtin_bit_cast(u32, f);
  u += 0x7FFFu + ((u >> 16) & 1u);
  return (u16)(u >> 16);
}
__device__ __forceinline__ float bflo(u32 w){ return __builtin_bit_cast(float, w << 16); }
__device__ __forceinline__ float bfhi(u32 w){ return __builtin_bit_cast(float, w & 0xFFFF0000u); }
__device__ __forceinline__ float bf1(u16 w){ return __builtin_bit_cast(float, ((u32)w) << 16); }
__device__ __forceinline__ float sigm(float x){ return 1.f / (1.f + __expf(-x)); }
__device__ __forceinline__ float tanh_fast(float x){
  float t = __expf(-2.f * fabsf(x));
  float r = (1.f - t) / (1.f + t);
  return copysignf(r, x);
}

// Kernel 0: pack weights (unchanged from R7).
__global__ __launch_bounds__(256) void prep_weights(
    const float* __restrict__ zl_w, const float* __restrict__ rl_w,
    const float* __restrict__ hl_w, const float* __restrict__ gh_w,
    const float* __restrict__ gx_w,
    u32* __restrict__ zlB, u32* __restrict__ rlB, u32* __restrict__ hlF,
    u32* __restrict__ Bpre, u32* __restrict__ ghF, float* __restrict__ gxd){
  int gid = blockIdx.x * 256 + threadIdx.x;   // 0..65535
  if (gid < 32768){
    int d   = gid & 3;
    int l   = (gid >> 2) & 63;
    int kt  = (gid >> 8) & 7;
    int ntg = (gid >> 11) & 15;
    int nn  = 16*ntg + (l & 15);
    int kk  = 32*kt + 8*(l >> 4) + 2*d;
    int c0 = 128 + kk;
    zlB[gid] = (u32)f2bf(zl_w[nn*CC + c0]) | ((u32)f2bf(zl_w[nn*CC + c0 + 1]) << 16);
    rlB[gid] = (u32)f2bf(rl_w[nn*CC + c0]) | ((u32)f2bf(rl_w[nn*CC + c0 + 1]) << 16);
    hlF[gid] = (u32)f2bf(hl_w[nn*CC + c0]) | ((u32)f2bf(hl_w[nn*CC + c0 + 1]) << 16);
  }
  #pragma unroll
  for (int q = 0; q < 2; ++q){
    int id = q*65536 + gid;
    if (id < 98304){
      int d2 = id & 3;
      int l  = (id >> 2) & 63;
      int kt = (id >> 8) & 7;
      int nt = id >> 11;            // 0..47
      int g  = nt >> 4;
      int nc = (nt & 15)*16 + (l & 15);
      int k  = 32*kt + 8*(l >> 4) + 2*d2;
      int sc = (k < 128) ? k : k + 256;
      const float* W = (g == 0) ? zl_w : ((g == 1) ? rl_w : hl_w);
      Bpre[id] = (u32)f2bf(W[nc*CC + sc]) | ((u32)f2bf(W[nc*CC + sc + 1]) << 16);
    }
  }
  if (gid < 16384){
    int d2 = gid & 3;
    int l  = (gid >> 2) & 63;
    int kt = (gid >> 8) & 3;
    int nt = gid >> 10;             // 0..15
    int nc = nt*16 + (l & 15);
    int k  = 32*kt + 8*(l >> 4) + 2*d2;
    ghF[gid] = (u32)f2bf(gh_w[nc*DD + k]) | ((u32)f2bf(gh_w[nc*DD + k + 1]) << 16);
  }
  if (gid < 128) gxd[gid] = gx_w[gid*DD + gid];
}

// Kernel 1: MFMA precompute. Wave-n remap nt=4i+wn so z(i<4)/r(i in 4..7) columns pair
// in-thread -> packed bf16x2 zr store. h pre-act stays f32 (tanh path precision).
__global__ __launch_bounds__(512, 2) void precompute_mfma(
    const float* __restrict__ input, const float* __restrict__ xmean,
    const float* __restrict__ gxd, const float* __restrict__ gx_b,
    const float* __restrict__ zl_b, const float* __restrict__ rl_b,
    const float* __restrict__ hl_b, const float* __restrict__ gh_b,
    const u32* __restrict__ Bpre, const u32* __restrict__ ghF,
    u32* __restrict__ zrp, float* __restrict__ hpre, float* __restrict__ dh){
  __shared__ __align__(16) u16 A1[4][8][64][8];   // 32 KB [mt][kt][lane][j]
  __shared__ __align__(16) u16 A2[4][4][64][8];   // 16 KB
  const int tid = threadIdx.x;
  const int r0 = blockIdx.x * 64;
  const int t  = r0 >> 9;
  const int b0 = r0 & 511;
  {
    int row = tid >> 3, dsg = tid & 7, d0 = dsg * 16;
    int b = b0 + row;
    const size_t ib = ((size_t)b * 4 * TT + t) * DD;
    int mt = row >> 4;
    #pragma unroll
    for (int gg = 0; gg < 2; ++gg){
      int db = d0 + 8*gg;
      float xv[8], lv[8], mv[8], dv[8], xm[8], gd[8], gb[8];
      #pragma unroll
      for (int q = 0; q < 2; ++q){
        *(float4*)&xv[q*4] = *(const float4*)&input[ib + 0*TT*DD + db + q*4];
        *(float4*)&lv[q*4] = *(const float4*)&input[ib + 1*TT*DD + db + q*4];
        *(float4*)&mv[q*4] = *(const float4*)&input[ib + 2*TT*DD + db + q*4];
        *(float4*)&dv[q*4] = *(const float4*)&input[ib + 3*TT*DD + db + q*4];
        *(float4*)&xm[q*4] = *(const float4*)&xmean[t*DD + db + q*4];
        *(float4*)&gd[q*4] = *(const float4*)&gxd[db + q*4];
        *(float4*)&gb[q*4] = *(const float4*)&gx_b[db + q*4];
      }
      union { u16 s[8]; bf16x8 v; } pe, pm, pd;
      #pragma unroll
      for (int j = 0; j < 8; ++j){
        float dxv = __expf(-fmaxf(dv[j]*gd[j] + gb[j], 0.f));
        float xe  = mv[j]*xv[j] + (1.f - mv[j])*(dxv*lv[j] + (1.f - dxv)*xm[j]);
        pe.s[j] = f2bf(xe);
        pm.s[j] = f2bf(mv[j]);
        pd.s[j] = f2bf(dv[j]);
      }
      int kt1 = db >> 5;
      int l1  = (row & 15) + 16*((db >> 3) & 3);
      *(bf16x8*)&A1[mt][kt1][l1][0]     = pe.v;
      *(bf16x8*)&A1[mt][4 + kt1][l1][0] = pm.v;
      *(bf16x8*)&A2[mt][kt1][l1][0]     = pd.v;
    }
  }
  __syncthreads();
  const int l = tid & 63, w = tid >> 6;
  const int wm = w >> 2, wn = w & 3;
  const int rowl = 4 * (l >> 4), coll = l & 15;
  // ---- phase 1: K=256, nt = 4i + wn
  f32x4 acc[2][12];
  #pragma unroll
  for (int m = 0; m < 2; ++m)
    #pragma unroll
    for (int i = 0; i < 12; ++i) acc[m][i] = (f32x4){0.f,0.f,0.f,0.f};
  #pragma unroll
  for (int kt = 0; kt < 8; ++kt){
    bf16x8 a0 = *(const bf16x8*)&A1[wm*2 + 0][kt][l][0];
    bf16x8 a1 = *(const bf16x8*)&A1[wm*2 + 1][kt][l][0];
    #pragma unroll
    for (int i = 0; i < 12; ++i){
      int nt = 4*i + wn;
      bf16x8 bf = *(const bf16x8*)(Bpre + ((nt*8 + kt)*64 + l)*4);
      acc[0][i] = __builtin_amdgcn_mfma_f32_16x16x32_bf16(a0, bf, acc[0][i], 0, 0, 0);
      acc[1][i] = __builtin_amdgcn_mfma_f32_16x16x32_bf16(a1, bf, acc[1][i], 0, 0, 0);
    }
  }
  #pragma unroll
  for (int m = 0; m < 2; ++m){
    int grow = r0 + wm*32 + m*16 + rowl;
    #pragma unroll
    for (int i = 0; i < 4; ++i){            // z: nt=4i+wn (<16), r: nt+16 — same lc
      int lc = (4*i + wn)*16 + coll;
      float bz = zl_b[lc], br = rl_b[lc];
      #pragma unroll
      for (int rg = 0; rg < 4; ++rg){
        u32 pk = (u32)f2bf(acc[m][i][rg] + bz) | ((u32)f2bf(acc[m][i+4][rg] + br) << 16);
        zrp[(size_t)(grow + rg)*HH + lc] = pk;
      }
    }
    #pragma unroll
    for (int i = 8; i < 12; ++i){           // h: nt = 4i+wn in 32..47, lc key = nt&15
      int lc = (4*(i-8) + wn)*16 + coll;
      float bh = hl_b[lc];
      #pragma unroll
      for (int rg = 0; rg < 4; ++rg)
        hpre[(size_t)(grow + rg)*HH + lc] = acc[m][i][rg] + bh;
    }
  }
  // ---- phase 2: K=128, dh (nt = wn*4 + i, unchanged)
  f32x4 ac2[2][4];
  #pragma unroll
  for (int m = 0; m < 2; ++m)
    #pragma unroll
    for (int i = 0; i < 4; ++i) ac2[m][i] = (f32x4){0.f,0.f,0.f,0.f};
  #pragma unroll
  for (int kt = 0; kt < 4; ++kt){
    bf16x8 a0 = *(const bf16x8*)&A2[wm*2 + 0][kt][l][0];
    bf16x8 a1 = *(const bf16x8*)&A2[wm*2 + 1][kt][l][0];
    #pragma unroll
    for (int i = 0; i < 4; ++i){
      int nt = wn*4 + i;
      bf16x8 bf = *(const bf16x8*)(ghF + ((nt*4 + kt)*64 + l)*4);
      ac2[0][i] = __builtin_amdgcn_mfma_f32_16x16x32_bf16(a0, bf, ac2[0][i], 0, 0, 0);
      ac2[1][i] = __builtin_amdgcn_mfma_f32_16x16x32_bf16(a1, bf, ac2[1][i], 0, 0, 0);
    }
  }
  #pragma unroll
  for (int m = 0; m < 2; ++m){
    int grow = r0 + wm*32 + m*16 + rowl;
    #pragma unroll
    for (int i = 0; i < 4; ++i){
      int lc = (wn*4 + i)*16 + coll;
      float bias = gh_b[lc];
      #pragma unroll
      for (int rg = 0; rg < 4; ++rg)
        dh[(size_t)(grow + rg)*HH + lc] = __expf(-fmaxf(ac2[m][i][rg] + bias, 0.f));
    }
  }
}

// Kernel 2: MFMA recurrence with 1-step register prefetch of all global operands.
// Loads for step t+1 are issued at the top of step t (above S1) and consumed next
// iteration -> HBM latency hidden under a full step of compute+barriers.
__global__ __launch_bounds__(512, 2) void recurrent_mfma(
    const u32* __restrict__ zrp, const float* __restrict__ hpre,
    const float* __restrict__ dh,
    const u32* __restrict__ zlB, const u32* __restrict__ rlB,
    const u32* __restrict__ hlF, u16* __restrict__ hout){
  __shared__ u32 smem[36864];   // 144 KB
  const int tid = threadIdx.x;
  const int l = tid & 63, w = tid >> 6;
  const int b0 = blockIdx.x * 16;
  const int rowb = 4 * (l >> 4);
  const int col0 = 32*w + (l & 15);

  #pragma unroll
  for (int i = 0; i < 64; ++i) smem[i*512 + tid] = hlF[i*512 + tid];
  #pragma unroll
  for (int i = 0; i < 4; ++i) smem[HDA_OFF + i*512 + tid] = 0;

  bf16x8 zb[2][8], rb[2][8];
  #pragma unroll
  for (int nt = 0; nt < 2; ++nt){
    #pragma unroll
    for (int kt = 0; kt < 8; ++kt){
      int off = (((w*2 + nt)*8 + kt)*64 + l)*4;
      zb[nt][kt] = *(const bf16x8*)(zlB + off);
      rb[nt][kt] = *(const bf16x8*)(rlB + off);
    }
  }
  __syncthreads();

  int scb[2];
  #pragma unroll
  for (int nt = 0; nt < 2; ++nt)
    scb[nt] = w*512 + (2*nt + ((l >> 3) & 1))*128 + rowb*8 + (l & 7);

  float hdreg[2][4] = {{0.f,0.f,0.f,0.f},{0.f,0.f,0.f,0.f}};
  float zreg[2][4];

  u16* pa16 = (u16*)(smem + PA_OFF);
  u16* hd16 = (u16*)(smem + HDA_OFF);

  // pipeline registers: cur = step t operands; pdC = dh@t+1
  u32 zrC[2][4]; float phC[2][4], pdC[2][4];
  #pragma unroll
  for (int nt = 0; nt < 2; ++nt){
    #pragma unroll
    for (int jr = 0; jr < 4; ++jr){
      size_t o  = ((size_t)b0 + rowb + jr)*HH + col0 + 16*nt;          // t=0
      size_t o2 = ((size_t)BB + b0 + rowb + jr)*HH + col0 + 16*nt;     // t=1
      zrC[nt][jr] = zrp[o];
      phC[nt][jr] = hpre[o];
      pdC[nt][jr] = dh[o2];
    }
  }

  for (int t = 0; t < TT; ++t){
    // ---- issue prefetch for step t+1 (lands during this step)
    u32 zrN[2][4]; float phN[2][4], pdN[2][4];
    {
      int tn  = (t < TT-1) ? t+1 : TT-1;
      int tn2 = (t < TT-2) ? t+2 : TT-1;
      #pragma unroll
      for (int nt = 0; nt < 2; ++nt){
        #pragma unroll
        for (int jr = 0; jr < 4; ++jr){
          size_t o  = ((size_t)tn *BB + b0 + rowb + jr)*HH + col0 + 16*nt;
          size_t o2 = ((size_t)tn2*BB + b0 + rowb + jr)*HH + col0 + 16*nt;
          zrN[nt][jr] = zrp[o];
          phN[nt][jr] = hpre[o];
          pdN[nt][jr] = dh[o2];
        }
      }
    }
    // ---- zr GEMM: C += hd(t) x W
    f32x4 cz[2] = {{0.f,0.f,0.f,0.f},{0.f,0.f,0.f,0.f}};
    f32x4 cr[2] = {{0.f,0.f,0.f,0.f},{0.f,0.f,0.f,0.f}};
    #pragma unroll
    for (int kt = 0; kt < 8; ++kt){
      bf16x8 a = *(const bf16x8*)(smem + HDA_OFF + kt*256 + l*4);
      cz[0] = __builtin_amdgcn_mfma_f32_16x16x32_bf16(a, zb[0][kt], cz[0], 0, 0, 0);
      cz[1] = __builtin_amdgcn_mfma_f32_16x16x32_bf16(a, zb[1][kt], cz[1], 0, 0, 0);
      cr[0] = __builtin_amdgcn_mfma_f32_16x16x32_bf16(a, rb[0][kt], cr[0], 0, 0, 0);
      cr[1] = __builtin_amdgcn_mfma_f32_16x16x32_bf16(a, rb[1][kt], cr[1], 0, 0, 0);
    }
    // ---- gates; write P = r*hd fragments
    #pragma unroll
    for (int nt = 0; nt < 2; ++nt){
      #pragma unroll
      for (int jr = 0; jr < 4; ++jr){
        float zv = sigm(bflo(zrC[nt][jr]) + cz[nt][jr]);
        float rv = sigm(bfhi(zrC[nt][jr]) + cr[nt][jr]);
        zreg[nt][jr] = zv;
        pa16[scb[nt] + jr*8] = f2bf(rv * hdreg[nt][jr]);
      }
    }
    BAR();   // S1: P visible; hd(t) reads drained (lgkm only)
    // ---- htilde GEMM
    f32x4 ch[2] = {{0.f,0.f,0.f,0.f},{0.f,0.f,0.f,0.f}};
    #pragma unroll
    for (int kt = 0; kt < 8; ++kt){
      bf16x8 a  = *(const bf16x8*)(smem + PA_OFF + kt*256 + l*4);
      bf16x8 bh0 = *(const bf16x8*)(smem + ((2*w+0)*8 + kt)*256 + l*4);
      bf16x8 bh1 = *(const bf16x8*)(smem + ((2*w+1)*8 + kt)*256 + l*4);
      ch[0] = __builtin_amdgcn_mfma_f32_16x16x32_bf16(a, bh0, ch[0], 0, 0, 0);
      ch[1] = __builtin_amdgcn_mfma_f32_16x16x32_bf16(a, bh1, ch[1], 0, 0, 0);
    }
    // ---- combine, emit h, stage hd(t+1)
    #pragma unroll
    for (int nt = 0; nt < 2; ++nt){
      #pragma unroll
      for (int jr = 0; jr < 4; ++jr){
        float ht = tanh_fast(phC[nt][jr] + ch[nt][jr]);
        float hd = hdreg[nt][jr];
        float zv = zreg[nt][jr];
        float hn = (1.f - zv)*hd + zv*ht;
        size_t o = ((size_t)t*BB + b0 + rowb + jr)*HH + col0 + 16*nt;
        hout[o] = f2bf(hn);
        float hdn = pdC[nt][jr] * hn;
        hdreg[nt][jr] = hdn;
        hd16[scb[nt] + jr*8] = f2bf(hdn);
      }
    }
    BAR();   // S2: hd(t+1) visible; P reads drained (lgkm only)
    // ---- rotate pipeline regs
    #pragma unroll
    for (int nt = 0; nt < 2; ++nt){
      #pragma unroll
      for (int jr = 0; jr < 4; ++jr){
        zrC[nt][jr] = zrN[nt][jr];
        phC[nt][jr] = phN[nt][jr];
        pdC[nt][jr] = pdN[nt][jr];
      }
    }
  }
}

// Kernel 3: out[b,t] = sigmoid(h[t,b,:] . fc_w + fc_b). One wave per row.
__global__ __launch_bounds__(256) void head(const u16* __restrict__ hout,
    const float* __restrict__ fc_w, const float* __restrict__ fc_b,
    float* __restrict__ out){
  int w = threadIdx.x >> 6, lane = threadIdx.x & 63;
  int rr = blockIdx.x * 4 + w;           // rr = t*BB + b
  const ushort4 hv = *(const ushort4*)&hout[(size_t)rr*HH + lane*4];
  const float4 fw = *(const float4*)&fc_w[lane*4];
  float s = bf1(hv.x)*fw.x + bf1(hv.y)*fw.y + bf1(hv.z)*fw.z + bf1(hv.w)*fw.w;
  #pragma unroll
  for (int o = 32; o >= 1; o >>= 1) s += __shfl_xor(s, o, 64);
  if (lane == 0){
    int t = rr >> 9, b = rr & 511;
    out[b*TT + t] = sigm(s + fc_b[0]);
  }
}

extern "C" void kernel_launch(void* const* d_in, const int* in_sizes, int n_in,
                              void* d_out, int out_size, void* d_ws, size_t ws_size,
                              hipStream_t stream) {
  const float* input = (const float*)d_in[0];
  const float* xmean = (const float*)d_in[1];
  const float* zl_w  = (const float*)d_in[2];
  const float* zl_b  = (const float*)d_in[3];
  const float* rl_w  = (const float*)d_in[4];
  const float* rl_b  = (const float*)d_in[5];
  const float* hl_w  = (const float*)d_in[6];
  const float* hl_b  = (const float*)d_in[7];
  const float* gx_w  = (const float*)d_in[8];
  const float* gx_b  = (const float*)d_in[9];
  const float* gh_w  = (const float*)d_in[10];
  const float* gh_b  = (const float*)d_in[11];
  const float* fc_w  = (const float*)d_in[12];
  const float* fc_b  = (const float*)d_in[13];
  float* out = (float*)d_out;

  const size_t S = (size_t)TT * BB * HH;   // 16,777,216
  u32*   zrp  = (u32*)d_ws;                // S u32 (z|r bf16 pair)
  float* hpre = (float*)(zrp + S);         // S f32
  float* dhp  = hpre + S;                  // S f32
  u16*   hout = (u16*)(dhp + S);           // S u16
  u32*   zlB  = (u32*)(hout + S);
  u32*   rlB  = zlB + 32768;
  u32*   hlF  = rlB + 32768;
  u32*   Bpre = hlF + 32768;
  u32*   ghF  = Bpre + 98304;
  float* gxd  = (float*)(ghF + 16384);

  prep_weights<<<256, 256, 0, stream>>>(zl_w, rl_w, hl_w, gh_w, gx_w,
                                        zlB, rlB, hlF, Bpre, ghF, gxd);
  precompute_mfma<<<1024, 512, 0, stream>>>(input, xmean, gxd, gx_b,
                                            zl_b, rl_b, hl_b, gh_b,
                                            Bpre, ghF,
                                            zrp, hpre, dhp);
  recurrent_mfma<<<32, 512, 0, stream>>>(zrp, hpre, dhp, zlB, rlB, hlF, hout);
  head<<<16384, 256, 0, stream>>>(hout, fc_w, fc_b, out);
}